// Round 6
// baseline (329.770 us; speedup 1.0000x reference)
//
#include <hip/hip_runtime.h>
#include <cstddef>
#include <cstdint>

#define B_DIM 8
#define L_DIM 2048
#define H_DIM 512
#define N_DIM 64
#define HN (H_DIM * N_DIM)          // 32768
#define BLH (B_DIM * L_DIM * H_DIM) // 8388608
#define M_DIM (B_DIM * L_DIM)       // 16384

typedef unsigned short u16;
typedef short bf16x8 __attribute__((ext_vector_type(8)));
typedef float floatx4 __attribute__((ext_vector_type(4)));

__device__ __forceinline__ float sigmoidf_(float v) {
    return 1.0f / (1.0f + __expf(-v));
}

// jax.nn.gelu default: approximate=True (tanh form)
__device__ __forceinline__ float gelu_tanh_(float x) {
    float x3 = x * x * x;
    float z = 0.7978845608028654f * fmaf(0.044715f, x3, x);
    float e = __expf(-2.0f * fabsf(z));
    float th = (1.0f - e) / (1.0f + e);
    th = copysignf(th, z);
    return 0.5f * x * (1.0f + th);
}

__device__ __forceinline__ u16 f2b(float f) {
    unsigned u = __float_as_uint(f);
    unsigned r = (u + 0x7fffu + ((u >> 16) & 1u)) >> 16;
    return (u16)r;
}
__device__ __forceinline__ float b2f(u16 u) {
    return __uint_as_float(((unsigned)u) << 16);
}
__device__ __forceinline__ void unpack2(unsigned u, float& a, float& b) {
    a = __uint_as_float(u << 16);
    b = __uint_as_float(u & 0xffff0000u);
}
__device__ __forceinline__ unsigned pack2(float a, float b) {
    return (unsigned)f2b(a) | ((unsigned)f2b(b) << 16);
}

__device__ __forceinline__ void csq(float& r, float& i) {
    float nr = r * r - i * i;
    i = 2.0f * r * i;
    r = nr;
}

// ---------------------------------------------------------------------------
// 0) fp32 -> bf16 cast (weights)
// ---------------------------------------------------------------------------
__global__ __launch_bounds__(256) void cast_kernel(
    const float* __restrict__ src, u16* __restrict__ dst)
{
    int i = blockIdx.x * 256 + threadIdx.x;
    float4 v = *(const float4*)(src + (size_t)i * 4);
    uint2 p;
    p.x = pack2(v.x, v.y);
    p.y = pack2(v.z, v.w);
    *(uint2*)(dst + (size_t)i * 4) = p;
}

// ---------------------------------------------------------------------------
// 1) Per-(h,n) SSM params: w = exp(dt*A), Ct2 = 2*C*(exp(dt*A)-1)/A
// ---------------------------------------------------------------------------
__global__ __launch_bounds__(256) void precompute_kernel(
    const float* __restrict__ log_dt, const float* __restrict__ A_re,
    const float* __restrict__ A_im, const float* __restrict__ C_re,
    const float* __restrict__ C_im, float* __restrict__ P)
{
    int i = blockIdx.x * 256 + threadIdx.x;
    if (i >= HN) return;
    int h = i >> 6;
    float dt = expf(log_dt[h]);
    float Ar = A_re[i], Ai = A_im[i];
    float ar = dt * Ar, ai = dt * Ai;
    float e = expf(ar);
    float wr = e * cosf(ai);
    float wi = e * sinf(ai);
    float em1r = wr - 1.0f, em1i = wi;
    float inv = 1.0f / fmaf(Ar, Ar, Ai * Ai);
    float qr = fmaf(em1r, Ar, em1i * Ai) * inv;
    float qi = fmaf(em1i, Ar, -(em1r * Ai)) * inv;
    float Cr = C_re[i], Ci = C_im[i];
    float ctr = Cr * qr - Ci * qi;
    float cti = Cr * qi + Ci * qr;
    P[i]          = wr;
    P[HN + i]     = wi;
    P[2 * HN + i] = 2.0f * ctr;
    P[3 * HN + i] = 2.0f * cti;
}

// ---------------------------------------------------------------------------
// 1b) K table: K[h][tau] = sum_n Re(Ct2_n * w_n^tau), tau = 0..63
// ---------------------------------------------------------------------------
__global__ __launch_bounds__(256) void ktab_kernel(
    const float* __restrict__ P, float* __restrict__ Ktab)
{
    int wv = threadIdx.x >> 6, lane = threadIdx.x & 63;
    int h = blockIdx.x * 4 + wv;
    int pidx = (h << 6) + lane;
    float wr = P[pidx], wi = P[HN + pidx];
    float c2r = P[2 * HN + pidx], c2i = P[3 * HN + pidx];
    float pr = 1.0f, pi = 0.0f;
    for (int tau = 0; tau < 64; ++tau) {
        float term = c2r * pr - c2i * pi;
        #pragma unroll
        for (int m = 32; m > 0; m >>= 1) term += __shfl_xor(term, m, 64);
        if (lane == 0) Ktab[(h << 6) + tau] = term;
        float nr = pr * wr - pi * wi, ni = pr * wi + pi * wr;
        pr = nr; pi = ni;
    }
}

// ---------------------------------------------------------------------------
// 1c) Toeplitz fill: Toep_bf[h][t][j] = (j<=t) ? bf16(K[h][t-j]) : 0
// ---------------------------------------------------------------------------
__global__ __launch_bounds__(256) void toepfill_kernel(
    const float* __restrict__ Ktab, u16* __restrict__ Toep_bf)
{
    int idx = blockIdx.x * 256 + threadIdx.x;   // 512*4096
    int h = idx >> 12;
    int rem = idx & 4095;
    int tt = rem >> 6, j = rem & 63;
    u16 v = 0;
    if (j <= tt) v = f2b(Ktab[(h << 6) + (tt - j)]);
    Toep_bf[idx] = v;
}

// ---------------------------------------------------------------------------
// 2) Transpose x (B,L,H) fp32 -> XT (B,H,L) bf16
// ---------------------------------------------------------------------------
__global__ __launch_bounds__(256) void xtrans_kernel(
    const float* __restrict__ x, u16* __restrict__ XT)
{
    __shared__ float tile[32][33];
    int b  = blockIdx.z;
    int l0 = blockIdx.x * 32;
    int h0 = blockIdx.y * 32;
    int tx = threadIdx.x & 31;
    int ty = threadIdx.x >> 5;
    #pragma unroll
    for (int r = 0; r < 4; ++r)
        tile[ty + r * 8][tx] = x[((size_t)b * L_DIM + l0 + ty + r * 8) * H_DIM + h0 + tx];
    __syncthreads();
    #pragma unroll
    for (int r = 0; r < 4; ++r)
        XT[((size_t)b * H_DIM + h0 + ty + r * 8) * L_DIM + l0 + tx] = f2b(tile[tx][ty + r * 8]);
}

// ---------------------------------------------------------------------------
// 3) Chunked SSM via MFMA (unchanged from R3)
// ---------------------------------------------------------------------------
__global__ __launch_bounds__(256) void ssm_chunk_kernel(
    const u16* __restrict__ XT, const float* __restrict__ P,
    const u16* __restrict__ Toep_bf, const float* __restrict__ D_skip,
    u16* __restrict__ YT)
{
    __shared__ u16 U[128 * 72];
    __shared__ u16 S[128 * 136];
    __shared__ u16 EVT[13312];
    u16* E  = EVT;
    u16* Tp = EVT;
    u16* V  = EVT + 4608;

    const int h    = blockIdx.x;
    const int b0   = blockIdx.y * 4;
    const int t    = threadIdx.x;
    const int lane = t & 63;
    const int wv   = t >> 6;
    const int lm   = lane & 15, lq = lane >> 4;

    const int pidx = (h << 6) + lane;
    const float wr  = P[pidx],          wi  = P[HN + pidx];
    const float c2r = P[2 * HN + pidx], c2i = P[3 * HN + pidx];

    #pragma unroll
    for (int r = 0; r < 4; ++r) {
        int idx = t + r * 256;
        int row = idx >> 3, ch = idx & 7;
        const u16* gp = XT + (((size_t)(b0 + (row >> 5)) * H_DIM + h) << 11)
                           + ((row & 31) << 6) + (ch << 3);
        *(uint4*)&U[row * 72 + ch * 8] = *(const uint4*)gp;
    }

    float bwr, bwi;
    {
        float g16r = wr, g16i = wi;
        csq(g16r, g16i); csq(g16r, g16i); csq(g16r, g16i); csq(g16r, g16i);
        if (wv == 0)      { bwr = 1.0f; bwi = 0.0f; }
        else if (wv == 1) { bwr = g16r; bwi = g16i; }
        else if (wv == 2) { bwr = g16r; bwi = g16i; csq(bwr, bwi); }
        else {
            float g32r = g16r, g32i = g16i; csq(g32r, g32i);
            bwr = g32r * g16r - g32i * g16i;
            bwi = g32r * g16i + g32i * g16r;
        }
    }

    {
        float pr = bwr, pi = bwi;
        #pragma unroll
        for (int jk = 0; jk < 16; ++jk) {
            int k = (wv << 4) + jk;
            int j = 63 - k;
            E[(2 * lane) * 72 + j]     = f2b(pr);
            E[(2 * lane + 1) * 72 + j] = f2b(pi);
            float nr = pr * wr - pi * wi, ni = pr * wi + pi * wr;
            pr = nr; pi = ni;
        }
    }
    __syncthreads();

    {
        const int wm = wv >> 1, wn = wv & 1;
        floatx4 acc[4][4] = {};
        #pragma unroll
        for (int ks = 0; ks < 2; ++ks) {
            bf16x8 af[4], bfv[4];
            #pragma unroll
            for (int i = 0; i < 4; ++i)
                af[i] = *(const bf16x8*)&E[(wm * 64 + i * 16 + lm) * 72 + ks * 32 + lq * 8];
            #pragma unroll
            for (int j = 0; j < 4; ++j)
                bfv[j] = *(const bf16x8*)&U[(wn * 64 + j * 16 + lm) * 72 + ks * 32 + lq * 8];
            #pragma unroll
            for (int i = 0; i < 4; ++i) {
                #pragma unroll
                for (int j = 0; j < 4; ++j)
                    acc[i][j] = __builtin_amdgcn_mfma_f32_16x16x32_bf16(af[i], bfv[j], acc[i][j], 0, 0, 0);
            }
        }
        #pragma unroll
        for (int i = 0; i < 4; ++i) {
            #pragma unroll
            for (int j = 0; j < 4; ++j) {
                int ncol = wn * 64 + j * 16 + lm;
                int m0   = wm * 64 + i * 16 + lq * 4;
                u16 pk[4];
                #pragma unroll
                for (int r = 0; r < 4; ++r) pk[r] = f2b(acc[i][j][r]);
                *(uint2*)&S[ncol * 136 + m0] = *(uint2*)pk;
            }
        }
    }
    __syncthreads();

    {
        float pr = bwr, pi = bwi;
        {
            float nr = pr * wr - pi * wi, ni = pr * wi + pi * wr;
            pr = nr; pi = ni;
        }
        #pragma unroll
        for (int jk = 1; jk <= 16; ++jk) {
            int tr = (wv << 4) + jk - 1;
            float qr = c2r * pr - c2i * pi;
            float qi = c2r * pi + c2i * pr;
            V[tr * 136 + 2 * lane]     = f2b(qr);
            V[tr * 136 + 2 * lane + 1] = f2b(-qi);
            float nr = pr * wr - pi * wi, ni = pr * wi + pi * wr;
            pr = nr; pi = ni;
        }
        #pragma unroll
        for (int r = 0; r < 2; ++r) {
            int idx = t + r * 256;
            int row = idx >> 3, ch = idx & 7;
            *(uint4*)&Tp[row * 72 + ch * 8] =
                *(const uint4*)&Toep_bf[((size_t)h << 12) + (row << 6) + (ch << 3)];
        }
        float wTr = wr, wTi = wi;
        csq(wTr, wTi); csq(wTr, wTi); csq(wTr, wTi);
        csq(wTr, wTi); csq(wTr, wTi); csq(wTr, wTi);   // w^64
        float Sr = 0.0f, Si = 0.0f;
        const int n2 = lane * 2;
        for (int c = 0; c < 32; ++c) {
            int base = (wv * 32 + c) * 136 + n2;
            unsigned lv = *(unsigned*)&S[base];
            float lr, li;
            unpack2(lv, lr, li);
            *(unsigned*)&S[base] = pack2(Sr, Si);
            float nSr = wTr * Sr - wTi * Si + lr;
            Si = wTr * Si + wTi * Sr + li;
            Sr = nSr;
        }
    }
    __syncthreads();

    {
        const float Dh = D_skip[h];
        floatx4 acc[4][2] = {};
        #pragma unroll
        for (int ks = 0; ks < 6; ++ks) {
            bf16x8 af[4], bfv[2];
            if (ks < 2) {
                #pragma unroll
                for (int i = 0; i < 4; ++i)
                    af[i] = *(const bf16x8*)&Tp[(i * 16 + lm) * 72 + ks * 32 + lq * 8];
                #pragma unroll
                for (int j = 0; j < 2; ++j)
                    bfv[j] = *(const bf16x8*)&U[(wv * 32 + j * 16 + lm) * 72 + ks * 32 + lq * 8];
            } else {
                #pragma unroll
                for (int i = 0; i < 4; ++i)
                    af[i] = *(const bf16x8*)&V[(i * 16 + lm) * 136 + (ks - 2) * 32 + lq * 8];
                #pragma unroll
                for (int j = 0; j < 2; ++j)
                    bfv[j] = *(const bf16x8*)&S[(wv * 32 + j * 16 + lm) * 136 + (ks - 2) * 32 + lq * 8];
            }
            #pragma unroll
            for (int i = 0; i < 4; ++i) {
                #pragma unroll
                for (int j = 0; j < 2; ++j)
                    acc[i][j] = __builtin_amdgcn_mfma_f32_16x16x32_bf16(af[i], bfv[j], acc[i][j], 0, 0, 0);
            }
        }
        #pragma unroll
        for (int j = 0; j < 2; ++j) {
            int ncol = wv * 32 + j * 16 + lm;
            int bloc = ncol >> 5, c = ncol & 31;
            size_t gbase = (((size_t)(b0 + bloc) * H_DIM + h) << 11) + (c << 6);
            #pragma unroll
            for (int i = 0; i < 4; ++i) {
                int t0 = i * 16 + lq * 4;
                u16 upk[4];
                *(uint2*)upk = *(const uint2*)&U[ncol * 72 + t0];
                u16 opk[4];
                #pragma unroll
                for (int r = 0; r < 4; ++r) {
                    float uvv = b2f(upk[r]);
                    float yv = gelu_tanh_(fmaf(Dh, uvv, acc[i][j][r]));
                    opk[r] = f2b(yv);
                }
                *(uint2*)&YT[gbase + t0] = *(uint2*)opk;
            }
        }
    }
}

// ---------------------------------------------------------------------------
// 4) Transpose YT (B,H,L) bf16 -> Y (B,L,H) bf16
// ---------------------------------------------------------------------------
__global__ __launch_bounds__(256) void ytrans_kernel(
    const u16* __restrict__ YT, u16* __restrict__ Y)
{
    __shared__ u16 tile[32][33];
    int b  = blockIdx.z;
    int l0 = blockIdx.x * 32;
    int h0 = blockIdx.y * 32;
    int tx = threadIdx.x & 31;
    int ty = threadIdx.x >> 5;
    #pragma unroll
    for (int r = 0; r < 4; ++r)
        tile[ty + r * 8][tx] = YT[((size_t)b * H_DIM + h0 + ty + r * 8) * L_DIM + l0 + tx];
    __syncthreads();
    #pragma unroll
    for (int r = 0; r < 4; ++r)
        Y[((size_t)b * L_DIM + l0 + ty + r * 8) * H_DIM + h0 + tx] = tile[tx][ty + r * 8];
}

// ---------------------------------------------------------------------------
// 5) GEMM1 + GLU + residual. NO LDS, NO BARRIERS: register-direct fragments.
//    BM=64, BN=128 (dual A/G). out = bf16( x + a*sigmoid(g) )
// ---------------------------------------------------------------------------
__global__ __launch_bounds__(256) void gemm1_glu_kernel(
    const u16* __restrict__ Y, const u16* __restrict__ Wo,
    const float* __restrict__ bo, const float* __restrict__ x,
    u16* __restrict__ out)
{
    const int lane = threadIdx.x & 63;
    const int wv   = threadIdx.x >> 6;
    const int lm   = lane & 15, lq = lane >> 4;
    const int m0   = blockIdx.x * 64;
    const int n0   = blockIdx.y * 128;
    const int nw   = n0 + wv * 32;

    floatx4 accA[4][2] = {};
    floatx4 accG[4][2] = {};
    #pragma unroll
    for (int kq = 0; kq < 8; ++kq) {        // K step 64
        bf16x8 af[2][4], ba[2][2], bg[2][2];
        #pragma unroll
        for (int ks = 0; ks < 2; ++ks) {
            int kk = kq * 64 + ks * 32 + lq * 8;
            #pragma unroll
            for (int i = 0; i < 4; ++i)
                af[ks][i] = *(const bf16x8*)&Y[(size_t)(m0 + i * 16 + lm) * 512 + kk];
            #pragma unroll
            for (int j = 0; j < 2; ++j) {
                int n = nw + j * 16 + lm;
                ba[ks][j] = *(const bf16x8*)&Wo[(size_t)n * 512 + kk];
                bg[ks][j] = *(const bf16x8*)&Wo[(size_t)(512 + n) * 512 + kk];
            }
        }
        #pragma unroll
        for (int ks = 0; ks < 2; ++ks) {
            #pragma unroll
            for (int i = 0; i < 4; ++i) {
                #pragma unroll
                for (int j = 0; j < 2; ++j) {
                    accA[i][j] = __builtin_amdgcn_mfma_f32_16x16x32_bf16(ba[ks][j], af[ks][i], accA[i][j], 0, 0, 0);
                    accG[i][j] = __builtin_amdgcn_mfma_f32_16x16x32_bf16(bg[ks][j], af[ks][i], accG[i][j], 0, 0, 0);
                }
            }
        }
    }
    #pragma unroll
    for (int i = 0; i < 4; ++i) {
        int m = m0 + i * 16 + lm;
        #pragma unroll
        for (int j = 0; j < 2; ++j) {
            int n = nw + j * 16 + lq * 4;
            float4 ba4 = *(const float4*)&bo[n];
            float4 bg4 = *(const float4*)&bo[512 + n];
            float4 xv  = *(const float4*)&x[(size_t)m * 512 + n];
            const float* baf = (const float*)&ba4;
            const float* bgf = (const float*)&bg4;
            const float* xf  = (const float*)&xv;
            u16 pk[4];
            #pragma unroll
            for (int r = 0; r < 4; ++r) {
                float av = accA[i][j][r] + baf[r];
                float gv = accG[i][j][r] + bgf[r];
                pk[r] = f2b(fmaf(av, sigmoidf_(gv), xf[r]));
            }
            *(uint2*)&out[(size_t)m * 512 + n] = *(uint2*)pk;
        }
    }
}

// ---------------------------------------------------------------------------
// 6) Fused: LN1 -> FFN -> LN2(x1n + y2) -> fp32.  One block = 32 rows.
//    XN holds x1n (PRESERVED through phase 2 — the final residual is the
//    LN1 OUTPUT, reference reassigns x). Phase-2 y2 kept in registers,
//    spilled to H1 (dead) after a barrier. XOR-swizzled LDS.
// ---------------------------------------------------------------------------
__global__ __launch_bounds__(256) void ffn_fused_kernel(
    const u16* __restrict__ X1, const u16* __restrict__ W1bf,
    const float* __restrict__ b1v, const u16* __restrict__ W2bf,
    const float* __restrict__ b2v,
    const float* __restrict__ ga1, const float* __restrict__ be1,
    const float* __restrict__ ga2, const float* __restrict__ be2,
    float* __restrict__ out)
{
    __shared__ u16 XN[32 * 512];
    __shared__ u16 H1[32 * 512];
    const int t    = threadIdx.x;
    const int lane = t & 63;
    const int wv   = t >> 6;
    const int lm   = lane & 15, lq = lane >> 4;
    const int m0   = blockIdx.x * 32;

    // ---- stage x1pre -> XN (lane-linear LDS dest; source chunk permuted)
    #pragma unroll
    for (int r = 0; r < 8; ++r) {
        int idx = t + r * 256;               // 0..2047
        int row = idx >> 6, cs = idx & 63;
        int cc  = (cs & ~7) | ((cs & 7) ^ (row & 7));
        const u16* gp = X1 + (size_t)(m0 + row) * 512 + cc * 8;
        __builtin_amdgcn_global_load_lds(
            (const __attribute__((address_space(1))) unsigned int*)gp,
            (__attribute__((address_space(3))) unsigned int*)(XN + (size_t)idx * 8),
            16, 0, 0);
    }
    __syncthreads();

    // ---- LN1 in place: XN := x1n
    {
        float g[8], bb[8];
        *(float4*)&g[0]  = *(const float4*)(ga1 + lane * 8);
        *(float4*)&g[4]  = *(const float4*)(ga1 + lane * 8 + 4);
        *(float4*)&bb[0] = *(const float4*)(be1 + lane * 8);
        *(float4*)&bb[4] = *(const float4*)(be1 + lane * 8 + 4);
        #pragma unroll
        for (int rr = 0; rr < 8; ++rr) {
            int row  = wv * 8 + rr;
            int slot = (lane & ~7) | ((lane & 7) ^ (row & 7));
            u16* p = &XN[row * 512 + slot * 8];
            uint4 raw = *(const uint4*)p;
            float v[8];
            unpack2(raw.x, v[0], v[1]); unpack2(raw.y, v[2], v[3]);
            unpack2(raw.z, v[4], v[5]); unpack2(raw.w, v[6], v[7]);
            float s = 0.0f, sq = 0.0f;
            #pragma unroll
            for (int i = 0; i < 8; ++i) { s += v[i]; sq = fmaf(v[i], v[i], sq); }
            #pragma unroll
            for (int m = 32; m > 0; m >>= 1) {
                s  += __shfl_xor(s, m, 64);
                sq += __shfl_xor(sq, m, 64);
            }
            float mu  = s * (1.0f / 512.0f);
            float var = sq * (1.0f / 512.0f) - mu * mu;
            float rs  = rsqrtf(var + 1e-5f);
            uint4 pk;
            pk.x = pack2(fmaf((v[0]-mu)*rs, g[0], bb[0]), fmaf((v[1]-mu)*rs, g[1], bb[1]));
            pk.y = pack2(fmaf((v[2]-mu)*rs, g[2], bb[2]), fmaf((v[3]-mu)*rs, g[3], bb[3]));
            pk.z = pack2(fmaf((v[4]-mu)*rs, g[4], bb[4]), fmaf((v[5]-mu)*rs, g[5], bb[5]));
            pk.w = pack2(fmaf((v[6]-mu)*rs, g[6], bb[6]), fmaf((v[7]-mu)*rs, g[7], bb[7]));
            *(uint4*)p = pk;
        }
    }
    __syncthreads();

    // ---- Phase 1: H1 = relu(XN @ W1^T + b1)
    #pragma unroll
    for (int nt = 0; nt < 4; ++nt) {
        floatx4 acc[2][2] = {};
        #pragma unroll
        for (int kq = 0; kq < 8; ++kq) {
            bf16x8 af[2][2], wf[2][2];
            #pragma unroll
            for (int ks = 0; ks < 2; ++ks) {
                #pragma unroll
                for (int i = 0; i < 2; ++i) {
                    int row  = i * 16 + lm;
                    int slot = kq * 8 + ((ks * 4 + lq) ^ (row & 7));
                    af[ks][i] = *(const bf16x8*)&XN[row * 512 + slot * 8];
                }
                #pragma unroll
                for (int j = 0; j < 2; ++j) {
                    int n = nt * 128 + wv * 32 + j * 16 + lm;
                    wf[ks][j] = *(const bf16x8*)&W1bf[(size_t)n * 512 + kq * 64 + ks * 32 + lq * 8];
                }
            }
            #pragma unroll
            for (int ks = 0; ks < 2; ++ks)
                #pragma unroll
                for (int i = 0; i < 2; ++i)
                    #pragma unroll
                    for (int j = 0; j < 2; ++j)
                        acc[i][j] = __builtin_amdgcn_mfma_f32_16x16x32_bf16(wf[ks][j], af[ks][i], acc[i][j], 0, 0, 0);
        }
        #pragma unroll
        for (int i = 0; i < 2; ++i) {
            int m = i * 16 + lm;
            #pragma unroll
            for (int j = 0; j < 2; ++j) {
                int n = nt * 128 + wv * 32 + j * 16 + lq * 4;
                float4 b4 = *(const float4*)&b1v[n];
                const float* bf4 = (const float*)&b4;
                u16 pk[4];
                #pragma unroll
                for (int r = 0; r < 4; ++r)
                    pk[r] = f2b(fmaxf(acc[i][j][r] + bf4[r], 0.0f));
                int cc   = n >> 3;
                int slot = (cc & ~7) | ((cc & 7) ^ (m & 7));
                *(uint2*)&H1[m * 512 + slot * 8 + (n & 7)] = *(uint2*)pk;
            }
        }
    }
    __syncthreads();

    // ---- Phase 2: y2 = H1 @ W2^T + b2, accumulated IN REGISTERS
    floatx4 acc2[4][2][2] = {};
    #pragma unroll
    for (int nt = 0; nt < 4; ++nt) {
        #pragma unroll
        for (int kq = 0; kq < 8; ++kq) {
            bf16x8 af[2][2], wf[2][2];
            #pragma unroll
            for (int ks = 0; ks < 2; ++ks) {
                #pragma unroll
                for (int i = 0; i < 2; ++i) {
                    int row  = i * 16 + lm;
                    int slot = kq * 8 + ((ks * 4 + lq) ^ (row & 7));
                    af[ks][i] = *(const bf16x8*)&H1[row * 512 + slot * 8];
                }
                #pragma unroll
                for (int j = 0; j < 2; ++j) {
                    int n = nt * 128 + wv * 32 + j * 16 + lm;
                    wf[ks][j] = *(const bf16x8*)&W2bf[(size_t)n * 512 + kq * 64 + ks * 32 + lq * 8];
                }
            }
            #pragma unroll
            for (int ks = 0; ks < 2; ++ks)
                #pragma unroll
                for (int i = 0; i < 2; ++i)
                    #pragma unroll
                    for (int j = 0; j < 2; ++j)
                        acc2[nt][i][j] = __builtin_amdgcn_mfma_f32_16x16x32_bf16(wf[ks][j], af[ks][i], acc2[nt][i][j], 0, 0, 0);
        }
    }
    __syncthreads();   // all H1 reads done -> H1 reusable for y2

    #pragma unroll
    for (int nt = 0; nt < 4; ++nt) {
        #pragma unroll
        for (int i = 0; i < 2; ++i) {
            int m = i * 16 + lm;
            #pragma unroll
            for (int j = 0; j < 2; ++j) {
                int n = nt * 128 + wv * 32 + j * 16 + lq * 4;
                float4 b4 = *(const float4*)&b2v[n];
                const float* bf4 = (const float*)&b4;
                u16 pk[4];
                #pragma unroll
                for (int r = 0; r < 4; ++r)
                    pk[r] = f2b(acc2[nt][i][j][r] + bf4[r]);
                int cc   = n >> 3;
                int slot = (cc & ~7) | ((cc & 7) ^ (m & 7));
                *(uint2*)&H1[m * 512 + slot * 8 + (n & 7)] = *(uint2*)pk;
            }
        }
    }
    __syncthreads();

    // ---- LN2: v = x1n (XN) + y2 (H1), all LDS-resident; out fp32
    {
        float g[8], bb[8];
        *(float4*)&g[0]  = *(const float4*)(ga2 + lane * 8);
        *(float4*)&g[4]  = *(const float4*)(ga2 + lane * 8 + 4);
        *(float4*)&bb[0] = *(const float4*)(be2 + lane * 8);
        *(float4*)&bb[4] = *(const float4*)(be2 + lane * 8 + 4);
        #pragma unroll
        for (int rr = 0; rr < 8; ++rr) {
            int row  = wv * 8 + rr;
            int slot = (lane & ~7) | ((lane & 7) ^ (row & 7));
            uint4 ry = *(const uint4*)&H1[row * 512 + slot * 8];
            uint4 rx = *(const uint4*)&XN[row * 512 + slot * 8];
            float v[8], xv[8];
            unpack2(ry.x, v[0], v[1]); unpack2(ry.y, v[2], v[3]);
            unpack2(ry.z, v[4], v[5]); unpack2(ry.w, v[6], v[7]);
            unpack2(rx.x, xv[0], xv[1]); unpack2(rx.y, xv[2], xv[3]);
            unpack2(rx.z, xv[4], xv[5]); unpack2(rx.w, xv[6], xv[7]);
            #pragma unroll
            for (int i = 0; i < 8; ++i) v[i] += xv[i];
            float s = 0.0f, sq = 0.0f;
            #pragma unroll
            for (int i = 0; i < 8; ++i) { s += v[i]; sq = fmaf(v[i], v[i], sq); }
            #pragma unroll
            for (int m = 32; m > 0; m >>= 1) {
                s  += __shfl_xor(s, m, 64);
                sq += __shfl_xor(sq, m, 64);
            }
            float mu  = s * (1.0f / 512.0f);
            float var = sq * (1.0f / 512.0f) - mu * mu;
            float rs  = rsqrtf(var + 1e-5f);
            float o[8];
            #pragma unroll
            for (int i = 0; i < 8; ++i)
                o[i] = fmaf((v[i] - mu) * rs, g[i], bb[i]);
            size_t gbase = (size_t)(m0 + row) * 512 + lane * 8;
            *(float4*)(out + gbase)     = *(float4*)&o[0];
            *(float4*)(out + gbase + 4) = *(float4*)&o[4];
        }
    }
}

// ---------------------------------------------------------------------------
extern "C" void kernel_launch(void* const* d_in, const int* in_sizes, int n_in,
                              void* d_out, int out_size, void* d_ws, size_t ws_size,
                              hipStream_t stream)
{
    (void)in_sizes; (void)n_in; (void)out_size; (void)ws_size;
    const float* x      = (const float*)d_in[0];
    const float* log_dt = (const float*)d_in[1];
    const float* A_re   = (const float*)d_in[2];
    const float* A_im   = (const float*)d_in[3];
    const float* C_re   = (const float*)d_in[4];
    const float* C_im   = (const float*)d_in[5];
    const float* D_skip = (const float*)d_in[6];
    const float* W_out  = (const float*)d_in[7];
    const float* b_out  = (const float*)d_in[8];
    const float* g1     = (const float*)d_in[9];
    const float* beta1  = (const float*)d_in[10];
    const float* g2     = (const float*)d_in[11];
    const float* beta2  = (const float*)d_in[12];
    const float* W1     = (const float*)d_in[13];
    const float* bc1    = (const float*)d_in[14];
    const float* W2     = (const float*)d_in[15];
    const float* bc2    = (const float*)d_in[16];
    float* out = (float*)d_out;

    char*  wsb    = (char*)d_ws;
    float* P      = (float*)wsb;
    float* Ktab   = (float*)(wsb + 4 * HN * 4);
    u16*   Toep   = (u16*)(wsb + 4 * HN * 4 + 512 * 64 * 4);
    u16*   Wobf   = Toep + 512 * 4096;
    u16*   W1bf   = Wobf + 1024 * 512;
    u16*   W2bf   = W1bf + 512 * 512;
    u16*   r1     = W2bf + 512 * 512;   // XT
    u16*   r2     = r1 + BLH;           // YT -> x1pre
    u16*   r3     = r2 + BLH;           // Y

    cast_kernel<<<512, 256, 0, stream>>>(W_out, Wobf);
    cast_kernel<<<256, 256, 0, stream>>>(W1, W1bf);
    cast_kernel<<<256, 256, 0, stream>>>(W2, W2bf);
    precompute_kernel<<<HN / 256, 256, 0, stream>>>(log_dt, A_re, A_im, C_re, C_im, P);
    ktab_kernel<<<128, 256, 0, stream>>>(P, Ktab);
    toepfill_kernel<<<8192, 256, 0, stream>>>(Ktab, Toep);
    xtrans_kernel<<<dim3(L_DIM / 32, H_DIM / 32, B_DIM), 256, 0, stream>>>(x, r1);
    ssm_chunk_kernel<<<dim3(H_DIM, 2), 256, 0, stream>>>(r1, P, Toep, D_skip, r2);
    ytrans_kernel<<<dim3(L_DIM / 32, H_DIM / 32, B_DIM), 256, 0, stream>>>(r2, r3);
    gemm1_glu_kernel<<<dim3(M_DIM / 64, 4), 256, 0, stream>>>(r3, Wobf, b_out, x, r2);
    ffn_fused_kernel<<<M_DIM / 32, 256, 0, stream>>>(r2, W1bf, bc1, W2bf, bc2,
                                                     g1, beta1, g2, beta2, out);
}

// Round 8
// 270.214 us; speedup vs baseline: 1.2204x; 1.2204x over previous
//
#include <hip/hip_runtime.h>
#include <cstddef>
#include <cstdint>

#define B_DIM 8
#define L_DIM 2048
#define H_DIM 512
#define N_DIM 64
#define HN (H_DIM * N_DIM)          // 32768
#define BLH (B_DIM * L_DIM * H_DIM) // 8388608
#define M_DIM (B_DIM * L_DIM)       // 16384

typedef unsigned short u16;
typedef short bf16x8 __attribute__((ext_vector_type(8)));
typedef float floatx4 __attribute__((ext_vector_type(4)));

__device__ __forceinline__ float sigmoidf_(float v) {
    return 1.0f / (1.0f + __expf(-v));
}

// jax.nn.gelu default: approximate=True (tanh form)
__device__ __forceinline__ float gelu_tanh_(float x) {
    float x3 = x * x * x;
    float z = 0.7978845608028654f * fmaf(0.044715f, x3, x);
    float e = __expf(-2.0f * fabsf(z));
    float th = (1.0f - e) / (1.0f + e);
    th = copysignf(th, z);
    return 0.5f * x * (1.0f + th);
}

__device__ __forceinline__ u16 f2b(float f) {
    unsigned u = __float_as_uint(f);
    unsigned r = (u + 0x7fffu + ((u >> 16) & 1u)) >> 16;
    return (u16)r;
}
__device__ __forceinline__ float b2f(u16 u) {
    return __uint_as_float(((unsigned)u) << 16);
}
__device__ __forceinline__ void unpack2(unsigned u, float& a, float& b) {
    a = __uint_as_float(u << 16);
    b = __uint_as_float(u & 0xffff0000u);
}
__device__ __forceinline__ unsigned pack2(float a, float b) {
    return (unsigned)f2b(a) | ((unsigned)f2b(b) << 16);
}

__device__ __forceinline__ void csq(float& r, float& i) {
    float nr = r * r - i * i;
    i = 2.0f * r * i;
    r = nr;
}

// ---------------------------------------------------------------------------
// setupA: 3 weight casts + SSM param precompute, partitioned by blockIdx
// ---------------------------------------------------------------------------
__global__ __launch_bounds__(256) void setupA_kernel(
    const float* __restrict__ W_out, u16* __restrict__ Wobf,
    const float* __restrict__ W1, u16* __restrict__ W1bf,
    const float* __restrict__ W2, u16* __restrict__ W2bf,
    const float* __restrict__ log_dt, const float* __restrict__ A_re,
    const float* __restrict__ A_im, const float* __restrict__ C_re,
    const float* __restrict__ C_im, float* __restrict__ P)
{
    int b = blockIdx.x, t = threadIdx.x;
    if (b < 1024) {
        const float* src; u16* dst; int i;
        if (b < 512)      { src = W_out; dst = Wobf; i = b * 256 + t; }
        else if (b < 768) { src = W1;    dst = W1bf; i = (b - 512) * 256 + t; }
        else              { src = W2;    dst = W2bf; i = (b - 768) * 256 + t; }
        float4 v = *(const float4*)(src + (size_t)i * 4);
        uint2 p;
        p.x = pack2(v.x, v.y);
        p.y = pack2(v.z, v.w);
        *(uint2*)(dst + (size_t)i * 4) = p;
        return;
    }
    int i = (b - 1024) * 256 + t;   // 0..32767
    int h = i >> 6;
    float dt = expf(log_dt[h]);
    float Ar = A_re[i], Ai = A_im[i];
    float ar = dt * Ar, ai = dt * Ai;
    float e = expf(ar);
    float wr = e * cosf(ai);
    float wi = e * sinf(ai);
    float em1r = wr - 1.0f, em1i = wi;
    float inv = 1.0f / fmaf(Ar, Ar, Ai * Ai);
    float qr = fmaf(em1r, Ar, em1i * Ai) * inv;
    float qi = fmaf(em1i, Ar, -(em1r * Ai)) * inv;
    float Cr = C_re[i], Ci = C_im[i];
    float ctr = Cr * qr - Ci * qi;
    float cti = Cr * qi + Ci * qr;
    P[i]          = wr;
    P[HN + i]     = wi;
    P[2 * HN + i] = 2.0f * ctr;
    P[3 * HN + i] = 2.0f * cti;
}

// ---------------------------------------------------------------------------
// setupB: K table (per-h wave reduce) + Toeplitz fill, fused via LDS.
// ---------------------------------------------------------------------------
__global__ __launch_bounds__(256) void setupB_kernel(
    const float* __restrict__ P, u16* __restrict__ Toep_bf)
{
    __shared__ float Kl[4][64];
    int wv = threadIdx.x >> 6, lane = threadIdx.x & 63;
    int h = blockIdx.x * 4 + wv;
    int pidx = (h << 6) + lane;
    float wr = P[pidx], wi = P[HN + pidx];
    float c2r = P[2 * HN + pidx], c2i = P[3 * HN + pidx];
    float pr = 1.0f, pi = 0.0f;
    for (int tau = 0; tau < 64; ++tau) {
        float term = c2r * pr - c2i * pi;
        #pragma unroll
        for (int m = 32; m > 0; m >>= 1) term += __shfl_xor(term, m, 64);
        if (lane == 0) Kl[wv][tau] = term;
        float nr = pr * wr - pi * wi, ni = pr * wi + pi * wr;
        pr = nr; pi = ni;
    }
    __syncthreads();
    int h0 = blockIdx.x * 4;
    #pragma unroll
    for (int e = 0; e < 64; ++e) {
        int gi = threadIdx.x + e * 256;      // 0..16383
        int hh = gi >> 12;
        int rem = gi & 4095;
        int tt = rem >> 6, j = rem & 63;
        u16 v = 0;
        if (j <= tt) v = f2b(Kl[hh][tt - j]);
        Toep_bf[((size_t)(h0 + hh) << 12) + rem] = v;
    }
}

// ---------------------------------------------------------------------------
// 2) Transpose x (B,L,H) fp32 -> XT (B,H,L) bf16
// ---------------------------------------------------------------------------
__global__ __launch_bounds__(256) void xtrans_kernel(
    const float* __restrict__ x, u16* __restrict__ XT)
{
    __shared__ float tile[32][33];
    int b  = blockIdx.z;
    int l0 = blockIdx.x * 32;
    int h0 = blockIdx.y * 32;
    int tx = threadIdx.x & 31;
    int ty = threadIdx.x >> 5;
    #pragma unroll
    for (int r = 0; r < 4; ++r)
        tile[ty + r * 8][tx] = x[((size_t)b * L_DIM + l0 + ty + r * 8) * H_DIM + h0 + tx];
    __syncthreads();
    #pragma unroll
    for (int r = 0; r < 4; ++r)
        XT[((size_t)b * H_DIM + h0 + ty + r * 8) * L_DIM + l0 + tx] = f2b(tile[tx][ty + r * 8]);
}

// ---------------------------------------------------------------------------
// 3) Chunked SSM via MFMA (verified R3/R4)
// ---------------------------------------------------------------------------
__global__ __launch_bounds__(256) void ssm_chunk_kernel(
    const u16* __restrict__ XT, const float* __restrict__ P,
    const u16* __restrict__ Toep_bf, const float* __restrict__ D_skip,
    u16* __restrict__ YT)
{
    __shared__ u16 U[128 * 72];
    __shared__ u16 S[128 * 136];
    __shared__ u16 EVT[13312];
    u16* E  = EVT;
    u16* Tp = EVT;
    u16* V  = EVT + 4608;

    const int h    = blockIdx.x;
    const int b0   = blockIdx.y * 4;
    const int t    = threadIdx.x;
    const int lane = t & 63;
    const int wv   = t >> 6;
    const int lm   = lane & 15, lq = lane >> 4;

    const int pidx = (h << 6) + lane;
    const float wr  = P[pidx],          wi  = P[HN + pidx];
    const float c2r = P[2 * HN + pidx], c2i = P[3 * HN + pidx];

    #pragma unroll
    for (int r = 0; r < 4; ++r) {
        int idx = t + r * 256;
        int row = idx >> 3, ch = idx & 7;
        const u16* gp = XT + (((size_t)(b0 + (row >> 5)) * H_DIM + h) << 11)
                           + ((row & 31) << 6) + (ch << 3);
        *(uint4*)&U[row * 72 + ch * 8] = *(const uint4*)gp;
    }

    float bwr, bwi;
    {
        float g16r = wr, g16i = wi;
        csq(g16r, g16i); csq(g16r, g16i); csq(g16r, g16i); csq(g16r, g16i);
        if (wv == 0)      { bwr = 1.0f; bwi = 0.0f; }
        else if (wv == 1) { bwr = g16r; bwi = g16i; }
        else if (wv == 2) { bwr = g16r; bwi = g16i; csq(bwr, bwi); }
        else {
            float g32r = g16r, g32i = g16i; csq(g32r, g32i);
            bwr = g32r * g16r - g32i * g16i;
            bwi = g32r * g16i + g32i * g16r;
        }
    }

    {
        float pr = bwr, pi = bwi;
        #pragma unroll
        for (int jk = 0; jk < 16; ++jk) {
            int k = (wv << 4) + jk;
            int j = 63 - k;
            E[(2 * lane) * 72 + j]     = f2b(pr);
            E[(2 * lane + 1) * 72 + j] = f2b(pi);
            float nr = pr * wr - pi * wi, ni = pr * wi + pi * wr;
            pr = nr; pi = ni;
        }
    }
    __syncthreads();

    {
        const int wm = wv >> 1, wn = wv & 1;
        floatx4 acc[4][4] = {};
        #pragma unroll
        for (int ks = 0; ks < 2; ++ks) {
            bf16x8 af[4], bfv[4];
            #pragma unroll
            for (int i = 0; i < 4; ++i)
                af[i] = *(const bf16x8*)&E[(wm * 64 + i * 16 + lm) * 72 + ks * 32 + lq * 8];
            #pragma unroll
            for (int j = 0; j < 4; ++j)
                bfv[j] = *(const bf16x8*)&U[(wn * 64 + j * 16 + lm) * 72 + ks * 32 + lq * 8];
            #pragma unroll
            for (int i = 0; i < 4; ++i) {
                #pragma unroll
                for (int j = 0; j < 4; ++j)
                    acc[i][j] = __builtin_amdgcn_mfma_f32_16x16x32_bf16(af[i], bfv[j], acc[i][j], 0, 0, 0);
            }
        }
        #pragma unroll
        for (int i = 0; i < 4; ++i) {
            #pragma unroll
            for (int j = 0; j < 4; ++j) {
                int ncol = wn * 64 + j * 16 + lm;
                int m0   = wm * 64 + i * 16 + lq * 4;
                u16 pk[4];
                #pragma unroll
                for (int r = 0; r < 4; ++r) pk[r] = f2b(acc[i][j][r]);
                *(uint2*)&S[ncol * 136 + m0] = *(uint2*)pk;
            }
        }
    }
    __syncthreads();

    {
        float pr = bwr, pi = bwi;
        {
            float nr = pr * wr - pi * wi, ni = pr * wi + pi * wr;
            pr = nr; pi = ni;
        }
        #pragma unroll
        for (int jk = 1; jk <= 16; ++jk) {
            int tr = (wv << 4) + jk - 1;
            float qr = c2r * pr - c2i * pi;
            float qi = c2r * pi + c2i * pr;
            V[tr * 136 + 2 * lane]     = f2b(qr);
            V[tr * 136 + 2 * lane + 1] = f2b(-qi);
            float nr = pr * wr - pi * wi, ni = pr * wi + pi * wr;
            pr = nr; pi = ni;
        }
        #pragma unroll
        for (int r = 0; r < 2; ++r) {
            int idx = t + r * 256;
            int row = idx >> 3, ch = idx & 7;
            *(uint4*)&Tp[row * 72 + ch * 8] =
                *(const uint4*)&Toep_bf[((size_t)h << 12) + (row << 6) + (ch << 3)];
        }
        float wTr = wr, wTi = wi;
        csq(wTr, wTi); csq(wTr, wTi); csq(wTr, wTi);
        csq(wTr, wTi); csq(wTr, wTi); csq(wTr, wTi);   // w^64
        float Sr = 0.0f, Si = 0.0f;
        const int n2 = lane * 2;
        for (int c = 0; c < 32; ++c) {
            int base = (wv * 32 + c) * 136 + n2;
            unsigned lv = *(unsigned*)&S[base];
            float lr, li;
            unpack2(lv, lr, li);
            *(unsigned*)&S[base] = pack2(Sr, Si);
            float nSr = wTr * Sr - wTi * Si + lr;
            Si = wTr * Si + wTi * Sr + li;
            Sr = nSr;
        }
    }
    __syncthreads();

    {
        const float Dh = D_skip[h];
        floatx4 acc[4][2] = {};
        #pragma unroll
        for (int ks = 0; ks < 6; ++ks) {
            bf16x8 af[4], bfv[2];
            if (ks < 2) {
                #pragma unroll
                for (int i = 0; i < 4; ++i)
                    af[i] = *(const bf16x8*)&Tp[(i * 16 + lm) * 72 + ks * 32 + lq * 8];
                #pragma unroll
                for (int j = 0; j < 2; ++j)
                    bfv[j] = *(const bf16x8*)&U[(wv * 32 + j * 16 + lm) * 72 + ks * 32 + lq * 8];
            } else {
                #pragma unroll
                for (int i = 0; i < 4; ++i)
                    af[i] = *(const bf16x8*)&V[(i * 16 + lm) * 136 + (ks - 2) * 32 + lq * 8];
                #pragma unroll
                for (int j = 0; j < 2; ++j)
                    bfv[j] = *(const bf16x8*)&S[(wv * 32 + j * 16 + lm) * 136 + (ks - 2) * 32 + lq * 8];
            }
            #pragma unroll
            for (int i = 0; i < 4; ++i) {
                #pragma unroll
                for (int j = 0; j < 2; ++j)
                    acc[i][j] = __builtin_amdgcn_mfma_f32_16x16x32_bf16(af[i], bfv[j], acc[i][j], 0, 0, 0);
            }
        }
        #pragma unroll
        for (int j = 0; j < 2; ++j) {
            int ncol = wv * 32 + j * 16 + lm;
            int bloc = ncol >> 5, c = ncol & 31;
            size_t gbase = (((size_t)(b0 + bloc) * H_DIM + h) << 11) + (c << 6);
            #pragma unroll
            for (int i = 0; i < 4; ++i) {
                int t0 = i * 16 + lq * 4;
                u16 upk[4];
                *(uint2*)upk = *(const uint2*)&U[ncol * 72 + t0];
                u16 opk[4];
                #pragma unroll
                for (int r = 0; r < 4; ++r) {
                    float uvv = b2f(upk[r]);
                    float yv = gelu_tanh_(fmaf(Dh, uvv, acc[i][j][r]));
                    opk[r] = f2b(yv);
                }
                *(uint2*)&YT[gbase + t0] = *(uint2*)opk;
            }
        }
    }
}

// ---------------------------------------------------------------------------
// 4) Transpose YT (B,H,L) bf16 -> Y (B,L,H) bf16
// ---------------------------------------------------------------------------
__global__ __launch_bounds__(256) void ytrans_kernel(
    const u16* __restrict__ YT, u16* __restrict__ Y)
{
    __shared__ u16 tile[32][33];
    int b  = blockIdx.z;
    int l0 = blockIdx.x * 32;
    int h0 = blockIdx.y * 32;
    int tx = threadIdx.x & 31;
    int ty = threadIdx.x >> 5;
    #pragma unroll
    for (int r = 0; r < 4; ++r)
        tile[ty + r * 8][tx] = YT[((size_t)b * H_DIM + h0 + ty + r * 8) * L_DIM + l0 + tx];
    __syncthreads();
    #pragma unroll
    for (int r = 0; r < 4; ++r)
        Y[((size_t)b * L_DIM + l0 + ty + r * 8) * H_DIM + h0 + tx] = tile[tx][ty + r * 8];
}

// ---------------------------------------------------------------------------
// Swizzled staging: 128x64 bf16 tile (row-major, ld=512) -> dense LDS [128][64]
// with chunk c of row r stored at slot c ^ (r&7).
// ---------------------------------------------------------------------------
__device__ __forceinline__ void stage_tile_128x64(
    const u16* __restrict__ g, u16* lds, int row0, int k0)
{
    const int t = threadIdx.x;
    #pragma unroll
    for (int r = 0; r < 4; ++r) {
        int idx  = t + r * 256;
        int row  = idx >> 3;
        int cs   = idx & 7;
        int csrc = cs ^ (row & 7);
        const u16* gp = g + (size_t)(row0 + row) * 512 + k0 + csrc * 8;
        __builtin_amdgcn_global_load_lds(
            (const __attribute__((address_space(1))) unsigned int*)gp,
            (__attribute__((address_space(3))) unsigned int*)(lds + (size_t)idx * 8),
            16, 0, 0);
    }
}

__device__ __forceinline__ bf16x8 ldfrag(const u16* lds, int row, int cc)
{
    int p = cc ^ (row & 7);
    return *(const bf16x8*)&lds[row * 64 + p * 8];
}

// ---------------------------------------------------------------------------
// 5) GEMM1 + GLU + residual — EXACT R4 version (measured 52 us, passed).
//    acc[4][4]: each wave covers 64 m-rows x 64 n-cols (4 j-tiles!).
// ---------------------------------------------------------------------------
__global__ __launch_bounds__(256) void gemm1_glu_kernel(
    const u16* __restrict__ A, const u16* __restrict__ Wo,
    const float* __restrict__ bo, const float* __restrict__ x,
    u16* __restrict__ out)
{
    __shared__ u16 As[128 * 64];
    __shared__ u16 Ba[128 * 64];
    __shared__ u16 Bg[128 * 64];
    const int t    = threadIdx.x;
    const int lane = t & 63;
    const int wv   = t >> 6;
    const int wm   = wv >> 1, wn = wv & 1;
    const int lm   = lane & 15, lq = lane >> 4;
    const int m0   = blockIdx.x * 128, n0 = blockIdx.y * 128;
    floatx4 accA[4][4] = {};
    floatx4 accG[4][4] = {};
    for (int k0 = 0; k0 < 512; k0 += 64) {
        stage_tile_128x64(A, As, m0, k0);
        stage_tile_128x64(Wo, Ba, n0, k0);
        stage_tile_128x64(Wo, Bg, 512 + n0, k0);
        __syncthreads();
        #pragma unroll
        for (int ks = 0; ks < 2; ++ks) {
            bf16x8 af[4], ba[4], bg[4];
            #pragma unroll
            for (int i = 0; i < 4; ++i)
                af[i] = ldfrag(As, wm * 64 + i * 16 + lm, ks * 4 + lq);
            #pragma unroll
            for (int j = 0; j < 4; ++j) {
                ba[j] = ldfrag(Ba, wn * 64 + j * 16 + lm, ks * 4 + lq);
                bg[j] = ldfrag(Bg, wn * 64 + j * 16 + lm, ks * 4 + lq);
            }
            #pragma unroll
            for (int i = 0; i < 4; ++i) {
                #pragma unroll
                for (int j = 0; j < 4; ++j) {
                    accA[i][j] = __builtin_amdgcn_mfma_f32_16x16x32_bf16(ba[j], af[i], accA[i][j], 0, 0, 0);
                    accG[i][j] = __builtin_amdgcn_mfma_f32_16x16x32_bf16(bg[j], af[i], accG[i][j], 0, 0, 0);
                }
            }
        }
        __syncthreads();
    }
    #pragma unroll
    for (int i = 0; i < 4; ++i) {
        int m = m0 + wm * 64 + i * 16 + lm;
        #pragma unroll
        for (int j = 0; j < 4; ++j) {
            int n = n0 + wn * 64 + j * 16 + lq * 4;
            float4 ba4 = *(const float4*)&bo[n];
            float4 bg4 = *(const float4*)&bo[512 + n];
            float4 xv  = *(const float4*)&x[(size_t)m * 512 + n];
            const float* baf = (const float*)&ba4;
            const float* bgf = (const float*)&bg4;
            const float* xf  = (const float*)&xv;
            u16 pk[4];
            #pragma unroll
            for (int r = 0; r < 4; ++r) {
                float av = accA[i][j][r] + baf[r];
                float gv = accG[i][j][r] + bgf[r];
                pk[r] = f2b(fmaf(av, sigmoidf_(gv), xf[r]));
            }
            *(uint2*)&out[(size_t)m * 512 + n] = *(uint2*)pk;
        }
    }
}

// ---------------------------------------------------------------------------
// 6) ffn2: LN1 -> relu(x1n@W1^T+b1) -> @W2^T+b2 -> LN2(x1n + y2) -> fp32 out.
//    512 threads (8 waves), BM=32 rows, full N=512. Weight k-tiles staged via
//    global_load_lds, shared by all waves. LDS 128KB -> 1 block/CU.
// ---------------------------------------------------------------------------
__global__ __launch_bounds__(512) void ffn2_kernel(
    const u16* __restrict__ X1, const u16* __restrict__ W1bf,
    const float* __restrict__ b1v, const u16* __restrict__ W2bf,
    const float* __restrict__ b2v,
    const float* __restrict__ ga1, const float* __restrict__ be1,
    const float* __restrict__ ga2, const float* __restrict__ be2,
    float* __restrict__ out)
{
    __shared__ u16 XB[32 * 512];   // x1pre -> x1n (32 KB)
    __shared__ u16 WS[512 * 64];   // weight k-tile (64 KB); reused for y2
    __shared__ u16 HB[32 * 512];   // relu hidden (32 KB)
    const int t    = threadIdx.x;
    const int lane = t & 63;
    const int wv   = t >> 6;        // 0..7
    const int lm   = lane & 15, lq = lane >> 4;
    const int m0   = blockIdx.x * 32;

    // ---- stage x1pre -> XB (swizzle: logical chunk cc at slot (cc&~7)|((cc&7)^(row&7)))
    #pragma unroll
    for (int r = 0; r < 4; ++r) {
        int idx = t + r * 512;               // 0..2047
        int row = idx >> 6, cs = idx & 63;
        int cc  = (cs & ~7) | ((cs & 7) ^ (row & 7));
        const u16* gp = X1 + (size_t)(m0 + row) * 512 + cc * 8;
        __builtin_amdgcn_global_load_lds(
            (const __attribute__((address_space(1))) unsigned int*)gp,
            (__attribute__((address_space(3))) unsigned int*)(XB + (size_t)idx * 8),
            16, 0, 0);
    }
    __syncthreads();

    // ---- LN1 in place: XB := x1n   (4 rows per wave)
    {
        float g[8], bb[8];
        *(float4*)&g[0]  = *(const float4*)(ga1 + lane * 8);
        *(float4*)&g[4]  = *(const float4*)(ga1 + lane * 8 + 4);
        *(float4*)&bb[0] = *(const float4*)(be1 + lane * 8);
        *(float4*)&bb[4] = *(const float4*)(be1 + lane * 8 + 4);
        #pragma unroll
        for (int rr = 0; rr < 4; ++rr) {
            int row  = wv * 4 + rr;
            int slot = (lane & ~7) | ((lane & 7) ^ (row & 7));
            u16* p = &XB[row * 512 + slot * 8];
            uint4 raw = *(const uint4*)p;
            float v[8];
            unpack2(raw.x, v[0], v[1]); unpack2(raw.y, v[2], v[3]);
            unpack2(raw.z, v[4], v[5]); unpack2(raw.w, v[6], v[7]);
            float s = 0.0f, sq = 0.0f;
            #pragma unroll
            for (int i = 0; i < 8; ++i) { s += v[i]; sq = fmaf(v[i], v[i], sq); }
            #pragma unroll
            for (int m = 32; m > 0; m >>= 1) {
                s  += __shfl_xor(s, m, 64);
                sq += __shfl_xor(sq, m, 64);
            }
            float mu  = s * (1.0f / 512.0f);
            float var = sq * (1.0f / 512.0f) - mu * mu;
            float rs  = rsqrtf(var + 1e-5f);
            uint4 pk;
            pk.x = pack2(fmaf((v[0]-mu)*rs, g[0], bb[0]), fmaf((v[1]-mu)*rs, g[1], bb[1]));
            pk.y = pack2(fmaf((v[2]-mu)*rs, g[2], bb[2]), fmaf((v[3]-mu)*rs, g[3], bb[3]));
            pk.z = pack2(fmaf((v[4]-mu)*rs, g[4], bb[4]), fmaf((v[5]-mu)*rs, g[5], bb[5]));
            pk.w = pack2(fmaf((v[6]-mu)*rs, g[6], bb[6]), fmaf((v[7]-mu)*rs, g[7], bb[7]));
            *(uint4*)p = pk;
        }
    }

    // ---- Phase 1: HB = relu(XB @ W1^T + b1), W1 k-tiles staged
    {
        floatx4 acc[2][4] = {};
        for (int kq = 0; kq < 8; ++kq) {
            __syncthreads();   // prior WS reads / LN1 writes done
            #pragma unroll
            for (int r = 0; r < 8; ++r) {
                int idx = t + r * 512;           // 0..4095
                int row = idx >> 3, c = idx & 7;
                int csrc = c ^ (row & 7);
                const u16* gp = W1bf + (size_t)row * 512 + kq * 64 + csrc * 8;
                __builtin_amdgcn_global_load_lds(
                    (const __attribute__((address_space(1))) unsigned int*)gp,
                    (__attribute__((address_space(3))) unsigned int*)(WS + (size_t)idx * 8),
                    16, 0, 0);
            }
            __syncthreads();
            #pragma unroll
            for (int ks = 0; ks < 2; ++ks) {
                bf16x8 af[2], wf[4];
                #pragma unroll
                for (int i = 0; i < 2; ++i) {
                    int row  = i * 16 + lm;
                    int slot = kq * 8 + ((ks * 4 + lq) ^ (row & 7));
                    af[i] = *(const bf16x8*)&XB[row * 512 + slot * 8];
                }
                #pragma unroll
                for (int j = 0; j < 4; ++j) {
                    int wrow = wv * 64 + j * 16 + lm;
                    int wslot = (ks * 4 + lq) ^ (wrow & 7);
                    wf[j] = *(const bf16x8*)&WS[wrow * 64 + wslot * 8];
                }
                #pragma unroll
                for (int i = 0; i < 2; ++i)
                    #pragma unroll
                    for (int j = 0; j < 4; ++j)
                        acc[i][j] = __builtin_amdgcn_mfma_f32_16x16x32_bf16(wf[j], af[i], acc[i][j], 0, 0, 0);
            }
        }
        #pragma unroll
        for (int i = 0; i < 2; ++i) {
            int m = i * 16 + lm;
            #pragma unroll
            for (int j = 0; j < 4; ++j) {
                int n = wv * 64 + j * 16 + lq * 4;
                float4 b4 = *(const float4*)&b1v[n];
                const float* bf4 = (const float*)&b4;
                u16 pk[4];
                #pragma unroll
                for (int r = 0; r < 4; ++r)
                    pk[r] = f2b(fmaxf(acc[i][j][r] + bf4[r], 0.0f));
                int cc   = n >> 3;
                int slot = (cc & ~7) | ((cc & 7) ^ (m & 7));
                *(uint2*)&HB[m * 512 + slot * 8 + (n & 7)] = *(uint2*)pk;
            }
        }
    }

    // ---- Phase 2: y2 = HB @ W2^T (+b2), W2 k-tiles staged; acc in regs
    floatx4 acc2[2][4] = {};
    for (int kq = 0; kq < 8; ++kq) {
        __syncthreads();   // HB writes (first iter) / prior WS reads done
        #pragma unroll
        for (int r = 0; r < 8; ++r) {
            int idx = t + r * 512;
            int row = idx >> 3, c = idx & 7;
            int csrc = c ^ (row & 7);
            const u16* gp = W2bf + (size_t)row * 512 + kq * 64 + csrc * 8;
            __builtin_amdgcn_global_load_lds(
                (const __attribute__((address_space(1))) unsigned int*)gp,
                (__attribute__((address_space(3))) unsigned int*)(WS + (size_t)idx * 8),
                16, 0, 0);
        }
        __syncthreads();
        #pragma unroll
        for (int ks = 0; ks < 2; ++ks) {
            bf16x8 af[2], wf[4];
            #pragma unroll
            for (int i = 0; i < 2; ++i) {
                int row  = i * 16 + lm;
                int slot = kq * 8 + ((ks * 4 + lq) ^ (row & 7));
                af[i] = *(const bf16x8*)&HB[row * 512 + slot * 8];
            }
            #pragma unroll
            for (int j = 0; j < 4; ++j) {
                int wrow = wv * 64 + j * 16 + lm;
                int wslot = (ks * 4 + lq) ^ (wrow & 7);
                wf[j] = *(const bf16x8*)&WS[wrow * 64 + wslot * 8];
            }
            #pragma unroll
            for (int i = 0; i < 2; ++i)
                #pragma unroll
                for (int j = 0; j < 4; ++j)
                    acc2[i][j] = __builtin_amdgcn_mfma_f32_16x16x32_bf16(wf[j], af[i], acc2[i][j], 0, 0, 0);
        }
    }
    __syncthreads();   // WS reads done -> reuse WS for y2

    #pragma unroll
    for (int i = 0; i < 2; ++i) {
        int m = i * 16 + lm;
        #pragma unroll
        for (int j = 0; j < 4; ++j) {
            int n = wv * 64 + j * 16 + lq * 4;
            float4 b4 = *(const float4*)&b2v[n];
            const float* bf4 = (const float*)&b4;
            u16 pk[4];
            #pragma unroll
            for (int r = 0; r < 4; ++r)
                pk[r] = f2b(acc2[i][j][r] + bf4[r]);
            int cc   = n >> 3;
            int slot = (cc & ~7) | ((cc & 7) ^ (m & 7));
            *(uint2*)&WS[m * 512 + slot * 8 + (n & 7)] = *(uint2*)pk;
        }
    }
    __syncthreads();

    // ---- LN2: v = x1n (XB) + y2 (WS); out fp32
    {
        float g[8], bb[8];
        *(float4*)&g[0]  = *(const float4*)(ga2 + lane * 8);
        *(float4*)&g[4]  = *(const float4*)(ga2 + lane * 8 + 4);
        *(float4*)&bb[0] = *(const float4*)(be2 + lane * 8);
        *(float4*)&bb[4] = *(const float4*)(be2 + lane * 8 + 4);
        #pragma unroll
        for (int rr = 0; rr < 4; ++rr) {
            int row  = wv * 4 + rr;
            int slot = (lane & ~7) | ((lane & 7) ^ (row & 7));
            uint4 ry = *(const uint4*)&WS[row * 512 + slot * 8];
            uint4 rx = *(const uint4*)&XB[row * 512 + slot * 8];
            float v[8], xv[8];
            unpack2(ry.x, v[0], v[1]); unpack2(ry.y, v[2], v[3]);
            unpack2(ry.z, v[4], v[5]); unpack2(ry.w, v[6], v[7]);
            unpack2(rx.x, xv[0], xv[1]); unpack2(rx.y, xv[2], xv[3]);
            unpack2(rx.z, xv[4], xv[5]); unpack2(rx.w, xv[6], xv[7]);
            #pragma unroll
            for (int i = 0; i < 8; ++i) v[i] += xv[i];
            float s = 0.0f, sq = 0.0f;
            #pragma unroll
            for (int i = 0; i < 8; ++i) { s += v[i]; sq = fmaf(v[i], v[i], sq); }
            #pragma unroll
            for (int m = 32; m > 0; m >>= 1) {
                s  += __shfl_xor(s, m, 64);
                sq += __shfl_xor(sq, m, 64);
            }
            float mu  = s * (1.0f / 512.0f);
            float var = sq * (1.0f / 512.0f) - mu * mu;
            float rs  = rsqrtf(var + 1e-5f);
            float o[8];
            #pragma unroll
            for (int i = 0; i < 8; ++i)
                o[i] = fmaf((v[i] - mu) * rs, g[i], bb[i]);
            size_t gbase = (size_t)(m0 + row) * 512 + lane * 8;
            *(float4*)(out + gbase)     = *(float4*)&o[0];
            *(float4*)(out + gbase + 4) = *(float4*)&o[4];
        }
    }
}

// ---------------------------------------------------------------------------
extern "C" void kernel_launch(void* const* d_in, const int* in_sizes, int n_in,
                              void* d_out, int out_size, void* d_ws, size_t ws_size,
                              hipStream_t stream)
{
    (void)in_sizes; (void)n_in; (void)out_size; (void)ws_size;
    const float* x      = (const float*)d_in[0];
    const float* log_dt = (const float*)d_in[1];
    const float* A_re   = (const float*)d_in[2];
    const float* A_im   = (const float*)d_in[3];
    const float* C_re   = (const float*)d_in[4];
    const float* C_im   = (const float*)d_in[5];
    const float* D_skip = (const float*)d_in[6];
    const float* W_out  = (const float*)d_in[7];
    const float* b_out  = (const float*)d_in[8];
    const float* g1     = (const float*)d_in[9];
    const float* beta1  = (const float*)d_in[10];
    const float* g2     = (const float*)d_in[11];
    const float* beta2  = (const float*)d_in[12];
    const float* W1     = (const float*)d_in[13];
    const float* bc1    = (const float*)d_in[14];
    const float* W2     = (const float*)d_in[15];
    const float* bc2    = (const float*)d_in[16];
    float* out = (float*)d_out;

    char*  wsb    = (char*)d_ws;
    float* P      = (float*)wsb;                         // 512 KB
    u16*   Toep   = (u16*)(wsb + 4 * HN * 4);            // 4 MB
    u16*   Wobf   = Toep + 512 * 4096;
    u16*   W1bf   = Wobf + 1024 * 512;
    u16*   W2bf   = W1bf + 512 * 512;
    u16*   r1     = W2bf + 512 * 512;   // XT
    u16*   r2     = r1 + BLH;           // YT -> x1pre
    u16*   r3     = r2 + BLH;           // Y

    setupA_kernel<<<1152, 256, 0, stream>>>(W_out, Wobf, W1, W1bf, W2, W2bf,
                                            log_dt, A_re, A_im, C_re, C_im, P);
    setupB_kernel<<<128, 256, 0, stream>>>(P, Toep);
    xtrans_kernel<<<dim3(L_DIM / 32, H_DIM / 32, B_DIM), 256, 0, stream>>>(x, r1);
    ssm_chunk_kernel<<<dim3(H_DIM, 2), 256, 0, stream>>>(r1, P, Toep, D_skip, r2);
    ytrans_kernel<<<dim3(L_DIM / 32, H_DIM / 32, B_DIM), 256, 0, stream>>>(r2, r3);
    gemm1_glu_kernel<<<dim3(M_DIM / 128, 4), 256, 0, stream>>>(r3, Wobf, b_out, x, r2);
    ffn2_kernel<<<M_DIM / 32, 512, 0, stream>>>(r2, W1bf, bc1, W2bf, bc2,
                                                g1, beta1, g2, beta2, out);
}